// Round 10
// baseline (121.917 us; speedup 1.0000x reference)
//
#include <hip/hip_runtime.h>
#include <math.h>

#define NJ      36
#define PTB     14          // points per block (two per j-thread)
#define ROW     291
#define THREADS 256
#define QS      0.0008f     // 4-bit linear quant scale (covers ±6 sigma)
#define QS2     (QS * QS)

typedef float f32x4 __attribute__((ext_vector_type(4)));
typedef unsigned int uint32x2 __attribute__((ext_vector_type(2)));
typedef uint32x2 uint2u8 __attribute__((aligned(8)));   // 8B-aligned pair
typedef uint32x2 uint2u4 __attribute__((aligned(4)));   // 4B-aligned pair (x-pair)

__device__ __forceinline__ unsigned int qnib(float x) {
    float q = rintf(x * (1.0f / QS) + 7.5f);
    q = fminf(fmaxf(q, 0.0f), 15.0f);
    return (unsigned int)q;
}

// ---- quantize+transpose cm (36,8,128,128) f32 -> cm4 (36,128,128) u32 nibbles ----
__global__ __launch_bounds__(256) void t_q4k(const float* __restrict__ src,
                                             unsigned int* __restrict__ dst) {
    __shared__ float tile[8][260];
    int j    = blockIdx.x >> 6;
    int pix0 = (blockIdx.x & 63) << 8;
    int t    = threadIdx.x;
    const float* s = src + (size_t)j * (8 * 16384) + pix0;
#pragma unroll
    for (int r = 0; r < 8; ++r) tile[r][t] = s[(size_t)r * 16384 + t];
    __syncthreads();
    unsigned int u = 0;
#pragma unroll
    for (int r = 0; r < 8; ++r) u |= qnib(tile[r][t]) << (4 * r);
    dst[j * 16384 + pix0 + t] = u;
}

// ---- cv (36,8,128) f32 -> cv4 (36,128) uint2 {q(i), q(i+1)} ----
__global__ __launch_bounds__(128) void t_cv4k(const float* __restrict__ src,
                                              uint2* __restrict__ dst) {
    __shared__ unsigned int spk[128];
    int j = blockIdx.x, i = threadIdx.x;
    unsigned int u = 0;
#pragma unroll
    for (int c = 0; c < 8; ++c) u |= qnib(src[j * 1024 + c * 128 + i]) << (4 * c);
    spk[i] = u;
    __syncthreads();
    dst[j * 128 + i] = make_uint2(u, spk[min(i + 1, 127)]);
}

// compute 2 features (channels cc and cc+4, nibbles at bits [0,4) and [16,20))
__device__ __forceinline__ void feat2(
    unsigned a00, unsigned a10, unsigned a01, unsigned a11,
    unsigned v0, unsigned v1, float wxp, float wy, float wv,
    float& fl, float& fh)
{
    float m00l = (float)(a00 & 15u), m00h = (float)((a00 >> 16) & 15u);
    float m10l = (float)(a10 & 15u), m10h = (float)((a10 >> 16) & 15u);
    float m01l = (float)(a01 & 15u), m01h = (float)((a01 >> 16) & 15u);
    float m11l = (float)(a11 & 15u), m11h = (float)((a11 >> 16) & 15u);
    float v0l  = (float)(v0  & 15u), v0h  = (float)((v0  >> 16) & 15u);
    float v1l  = (float)(v1  & 15u), v1h  = (float)((v1  >> 16) & 15u);
    float x0l = m00l + (m01l - m00l) * wxp;
    float x1l = m10l + (m11l - m10l) * wxp;
    float ml  = x0l + (x1l - x0l) * wy - 7.5f;
    float vl  = v0l + (v1l - v0l) * wv - 7.5f;
    fl = ml * vl * QS2;
    float x0h = m00h + (m01h - m00h) * wxp;
    float x1h = m10h + (m11h - m10h) * wxp;
    float mh  = x0h + (x1h - x0h) * wy - 7.5f;
    float vh  = v0h + (v1h - v0h) * wv - 7.5f;
    fh = mh * vh * QS2;
}

// ---- v9: L2-resident 2.36MB table; 2x 8B x-pair loads per bilinear ----
__global__ __launch_bounds__(THREADS) void freqvm_v9(
    const float* __restrict__ points,
    const unsigned char* __restrict__ cv4,   // [j][i] uint2 {q(i),q(i+1)}
    const unsigned char* __restrict__ cm4,   // [j][y][x] u32 nibbles
    float* __restrict__ out, int n)
{
    __shared__ float s_pos[PTB][NJ];                      // 2016 B
    __shared__ __align__(16) float s_out[PTB * ROW];      // 16296 B

    const int t   = threadIdx.x;
    const int blk = blockIdx.x;

    // ---- phase 0: sincos once per point (42 threads) ----
    if (t < PTB * 3) {
        int pt = t / 3, a = t - pt * 3;
        int gp  = blk * PTB + pt;
        int gpc = (gp < n) ? gp : (n - 1);
        float x = points[gpc * 3 + a];
        s_out[pt * ROW + a] = x;                          // passthrough coords
        float fs = 1.0f;
#pragma unroll
        for (int f = 0; f < 6; ++f) {
            float sv, cvv;
            __sincosf(x * fs, &sv, &cvv);
            fs *= 2.0f;
            s_pos[pt][f * 6 + a]     = (sv  + 1.0f) * 63.5f;   // sin row
            s_pos[pt][f * 6 + 3 + a] = (cvv + 1.0f) * 63.5f;   // cos row
        }
    }
    __syncthreads();

    // ---- phase 1: one (pp, jj) per thread; pp covers points 2pp, 2pp+1 ----
    if (t < (PTB / 2) * NJ) {
        const int pp = t / NJ, jj = t - pp * NJ;
        const int f = jj / 6, k = jj - f * 6;
        static constexpr int XI[6] = {1, 2, 0, 4, 5, 3};
        static constexpr int YI[6] = {2, 0, 1, 5, 3, 4};
        const int jx = f * 6 + XI[k], jy = f * 6 + YI[k];
        const int ptA = pp * 2, ptB = ptA + 1;

        float pvA = s_pos[ptA][jj], pxA = s_pos[ptA][jx], pyA = s_pos[ptA][jy];
        float pvB = s_pos[ptB][jj], pxB = s_pos[ptB][jx], pyB = s_pos[ptB][jy];

        int ivA = min((int)pvA, 127); float wvA = pvA - (float)ivA;
        int ixA = min((int)pxA, 127); float wxA = pxA - (float)ixA;
        int iyA = min((int)pyA, 127); float wyA = pyA - (float)iyA;
        int iyA1 = min(iyA + 1, 127);
        int lbxA = min(ixA, 126);  float wxpA = wxA + (float)(ixA - lbxA);

        int ivB = min((int)pvB, 127); float wvB = pvB - (float)ivB;
        int ixB = min((int)pxB, 127); float wxB = pxB - (float)ixB;
        int iyB = min((int)pyB, 127); float wyB = pyB - (float)iyB;
        int iyB1 = min(iyB + 1, 127);
        int lbxB = min(ixB, 126);  float wxpB = wxB + (float)(ixB - lbxB);

        // --- issue all 6 loads back-to-back ---
        const unsigned char* mjb = cm4 + ((size_t)jj << 16);   // 16384 u32/j
        const unsigned char* vjb = cv4 + ((size_t)jj << 10);
        uint2u4 R0A = *(const uint2u4*)(mjb + (size_t)((((iyA  << 7) + lbxA) << 2)));
        uint2u4 R1A = *(const uint2u4*)(mjb + (size_t)((((iyA1 << 7) + lbxA) << 2)));
        uint2u8 VA  = *(const uint2u8*)(vjb + (ivA << 3));
        uint2u4 R0B = *(const uint2u4*)(mjb + (size_t)((((iyB  << 7) + lbxB) << 2)));
        uint2u4 R1B = *(const uint2u4*)(mjb + (size_t)((((iyB1 << 7) + lbxB) << 2)));
        uint2u8 VB  = *(const uint2u8*)(vjb + (ivB << 3));

        float* orowA = s_out + ptA * ROW + 3 + jj;
        float* orowB = s_out + ptB * ROW + 3 + jj;

        // corners: a00=(y,x0) a01=(y,x1) a10=(y1,x0) a11=(y1,x1)
        unsigned a00A = R0A.x, a01A = R0A.y, a10A = R1A.x, a11A = R1A.y;
        unsigned v0A = VA.x, v1A = VA.y;
        unsigned a00B = R0B.x, a01B = R0B.y, a10B = R1B.x, a11B = R1B.y;
        unsigned v0B = VB.x, v1B = VB.y;

#pragma unroll
        for (int cc = 0; cc < 4; ++cc) {
            float fl, fh;
            feat2(a00A, a10A, a01A, a11A, v0A, v1A, wxpA, wyA, wvA, fl, fh);
            orowA[cc * 36]       = fl;
            orowA[(cc + 4) * 36] = fh;
            feat2(a00B, a10B, a01B, a11B, v0B, v1B, wxpB, wyB, wvB, fl, fh);
            orowB[cc * 36]       = fl;
            orowB[(cc + 4) * 36] = fh;
            a00A >>= 4; a10A >>= 4; a01A >>= 4; a11A >>= 4; v0A >>= 4; v1A >>= 4;
            a00B >>= 4; a10B >>= 4; a01B >>= 4; a11B >>= 4; v0B >>= 4; v1B >>= 4;
        }
    }
    __syncthreads();

    // ---- phase 2: vectorized non-temporal writeout ----
    size_t base  = (size_t)blk * (PTB * ROW);
    size_t total = (size_t)n * ROW;
    size_t rem   = total - base;
    float* o = out + base;
    if (rem >= (size_t)(PTB * ROW)) {
        // full block: PTB*ROW = 4074 floats; base%4 is 0 or 2
        const int head = (int)(base & 3);                 // 0 or 2
        if (head) {
            if (t == 0) {
                __builtin_nontemporal_store(s_out[0], &o[0]);
                __builtin_nontemporal_store(s_out[1], &o[1]);
            }
        }
        const float* sv = s_out + head;
        f32x4* o4 = (f32x4*)(o + head);
        for (int i = t; i < 1018; i += THREADS) {
            f32x4 v = { sv[4 * i], sv[4 * i + 1], sv[4 * i + 2], sv[4 * i + 3] };
            __builtin_nontemporal_store(v, &o4[i]);
        }
        if (!head) {
            if (t == THREADS - 1) {
                __builtin_nontemporal_store(s_out[4072], &o[4072]);
                __builtin_nontemporal_store(s_out[4073], &o[4073]);
            }
        }
    } else {
        int lim = (int)rem;
        for (int i = t; i < lim; i += THREADS)
            __builtin_nontemporal_store(s_out[i], &o[i]);
    }
}

// ---------------- fallback (no workspace): fp32 original layout ----------------
__global__ __launch_bounds__(256) void freqvm_slow(
    const float* __restrict__ points,
    const float* __restrict__ cv,    // [j][c][i]
    const float* __restrict__ cm,    // [j][c][y][x]
    float* __restrict__ out, int n)
{
    __shared__ float s_pos[32][NJ];
    __shared__ __align__(16) float s_out[32 * ROW];
    const int t  = threadIdx.x;
    const int p0 = blockIdx.x * 32;
    if (t < 96) {
        int pt = t / 3, a = t - pt * 3;
        int gp = p0 + pt;
        float x = (gp < n) ? points[gp * 3 + a] : 0.0f;
        s_out[pt * ROW + a] = x;
#pragma unroll
        for (int f = 0; f < 6; ++f) {
            float sv, cvv;
            __sincosf(x * (float)(1 << f), &sv, &cvv);
            s_pos[pt][f * 6 + a]     = (sv  + 1.0f) * 63.5f;
            s_pos[pt][f * 6 + 3 + a] = (cvv + 1.0f) * 63.5f;
        }
    }
    __syncthreads();
    static constexpr int XI[6] = {1, 2, 0, 4, 5, 3};
    static constexpr int YI[6] = {2, 0, 1, 5, 3, 4};
    const int c  = t & 7;
    const int pt = t >> 3;
    for (int f = 0; f < 6; ++f) {
#pragma unroll
        for (int k = 0; k < 6; ++k) {
            const int j = f * 6 + k;
            float pj = s_pos[pt][j];
            int   i0 = min((int)pj, 127); float wv = pj - (float)i0;
            int   i1 = min(i0 + 1, 127);
            const float* vb = cv + (size_t)(j * 8 + c) * 128;
            float vecf = vb[i0] + (vb[i1] - vb[i0]) * wv;
            float px = s_pos[pt][f * 6 + XI[k]];
            float py = s_pos[pt][f * 6 + YI[k]];
            int   ix0 = min((int)px, 127); float wx = px - (float)ix0;
            int   iy0 = min((int)py, 127); float wy = py - (float)iy0;
            int   ix1 = min(ix0 + 1, 127);
            int   iy1 = min(iy0 + 1, 127);
            const float* mb = cm + (size_t)(j * 8 + c) * 16384;
            float m00 = mb[iy0 * 128 + ix0], m01 = mb[iy0 * 128 + ix1];
            float m10 = mb[iy1 * 128 + ix0], m11 = mb[iy1 * 128 + ix1];
            float mx0  = m00 + (m01 - m00) * wx;
            float mx1  = m10 + (m11 - m10) * wx;
            s_out[pt * ROW + 3 + c * 36 + j] = vecf * (mx0 + (mx1 - mx0) * wy);
        }
    }
    __syncthreads();
    size_t base  = (size_t)blockIdx.x * (32 * ROW);
    size_t total = (size_t)n * ROW;
    size_t rem   = total - base;
    int lim = (int)((rem < (size_t)(32 * ROW) ? rem : (size_t)(32 * ROW)));
    float* o = out + base;
    for (int i = t; i < lim; i += 256) o[i] = s_out[i];
}

extern "C" void kernel_launch(void* const* d_in, const int* in_sizes, int n_in,
                              void* d_out, int out_size, void* d_ws, size_t ws_size,
                              hipStream_t stream) {
    (void)n_in; (void)out_size;
    const float* points = (const float*)d_in[0];
    const float* cv     = (const float*)d_in[1];
    const float* cm     = (const float*)d_in[2];
    float* out = (float*)d_out;
    const int n = in_sizes[0] / 3;

    const size_t cm4_bytes = (size_t)NJ * 16384 * 4;   // 2.36 MB (u32 per (y,x))
    const size_t cv4_bytes = (size_t)NJ * 128 * 8;     // 36.9 KB

    if (ws_size >= cm4_bytes + cv4_bytes + 64) {
        unsigned char* cm4 = (unsigned char*)d_ws;
        unsigned char* cv4 = (unsigned char*)d_ws + cm4_bytes;
        t_q4k <<<NJ * 64, 256, 0, stream>>>(cm, (unsigned int*)cm4);
        t_cv4k<<<NJ,      128, 0, stream>>>(cv, (uint2*)cv4);
        int nblocks = (n + PTB - 1) / PTB;
        freqvm_v9<<<nblocks, THREADS, 0, stream>>>(points, cv4, cm4, out, n);
    } else {
        int nblocks = (n + 31) / 32;
        freqvm_slow<<<nblocks, 256, 0, stream>>>(points, cv, cm, out, n);
    }
}

// Round 11
// 115.198 us; speedup vs baseline: 1.0583x; 1.0583x over previous
//
#include <hip/hip_runtime.h>
#include <math.h>

#define NJ      36
#define PTB     14          // points per block (two per j-thread)
#define ROW     291
#define THREADS 256
#define QSM     0.0025f     // 2-bit cm scale
#define QSV     0.0008f     // 4-bit cv scale
#define QQ      (QSM * QSV)

typedef float f32x4 __attribute__((ext_vector_type(4)));
typedef unsigned int uint32x2 __attribute__((ext_vector_type(2)));
typedef uint32x2 uint2u8 __attribute__((aligned(8)));

__device__ __forceinline__ unsigned q2nib(float x) {
    float q = rintf(x * (1.0f / QSM) + 1.5f);
    q = fminf(fmaxf(q, 0.0f), 3.0f);
    return (unsigned)q;
}
__device__ __forceinline__ unsigned q4nib(float x) {
    float q = rintf(x * (1.0f / QSV) + 7.5f);
    q = fminf(fmaxf(q, 0.0f), 15.0f);
    return (unsigned)q;
}

// ---- pass 1: cm (36,8,128,128) f32 -> q2 rowpack u16 [36][16384] ----
__global__ __launch_bounds__(256) void t_q2k(const float* __restrict__ src,
                                             unsigned short* __restrict__ dst) {
    __shared__ float tile[8][260];
    int j    = blockIdx.x >> 6;
    int pix0 = (blockIdx.x & 63) << 8;
    int t    = threadIdx.x;
    const float* s = src + (size_t)j * (8 * 16384) + pix0;
#pragma unroll
    for (int r = 0; r < 8; ++r) tile[r][t] = s[(size_t)r * 16384 + t];
    __syncthreads();
    unsigned u = 0;
#pragma unroll
    for (int r = 0; r < 8; ++r) u |= q2nib(tile[r][t]) << (2 * r);
    dst[j * 16384 + pix0 + t] = (unsigned short)u;
}

// ---- pass 2: build 4-corner 8B units (clamp baked in): uint2 [36][16384] ----
// lo = {row y: x, x+1}, hi = {row y+1: x, x+1}; channel c at bits 2c / 16+2c
__global__ __launch_bounds__(256) void t_c4k(const unsigned short* __restrict__ q,
                                             uint2* __restrict__ dst) {
    int j = blockIdx.x >> 6;
    int p = ((blockIdx.x & 63) << 8) + threadIdx.x;
    int y = p >> 7, x = p & 127;
    int xn = min(x + 1, 127), yn = min(y + 1, 127);
    const unsigned short* qj = q + j * 16384;
    unsigned lo = (unsigned)qj[(y  << 7) + x] | ((unsigned)qj[(y  << 7) + xn] << 16);
    unsigned hi = (unsigned)qj[(yn << 7) + x] | ((unsigned)qj[(yn << 7) + xn] << 16);
    dst[j * 16384 + p] = make_uint2(lo, hi);
}

// ---- cv (36,8,128) f32 -> u32 nibbles [36][128] (non-replicated) ----
__global__ __launch_bounds__(128) void t_cvn(const float* __restrict__ src,
                                             unsigned int* __restrict__ dst) {
    int j = blockIdx.x, i = threadIdx.x;
    unsigned u = 0;
#pragma unroll
    for (int c = 0; c < 8; ++c) u |= q4nib(src[j * 1024 + c * 128 + i]) << (4 * c);
    dst[j * 128 + i] = u;
}

// ---- v11: ONE aligned 8B global load per bilinear; cv via LDS ----
__global__ __launch_bounds__(THREADS) void freqvm_v11(
    const float* __restrict__ points,
    const unsigned int* __restrict__ cvn,    // [j][i] u32 nibbles
    const uint2u8* __restrict__ cm2,         // [j][y*128+x] 4-corner 2-bit units
    float* __restrict__ out, int n)
{
    __shared__ float s_pos[PTB][NJ];                      // 2016 B
    __shared__ __align__(16) float s_out[PTB * ROW];      // 16296 B
    __shared__ unsigned s_cv[NJ * 128];                   // 18432 B

    const int t   = threadIdx.x;
    const int blk = blockIdx.x;

    // ---- phase 0: stage cv table + sincos per point ----
    for (int i = t; i < NJ * 128; i += THREADS) s_cv[i] = cvn[i];
    if (t < PTB * 3) {
        int pt = t / 3, a = t - pt * 3;
        int gp  = blk * PTB + pt;
        int gpc = (gp < n) ? gp : (n - 1);
        float x = points[gpc * 3 + a];
        s_out[pt * ROW + a] = x;                          // passthrough coords
        float fs = 1.0f;
#pragma unroll
        for (int f = 0; f < 6; ++f) {
            float sv, cvv;
            __sincosf(x * fs, &sv, &cvv);
            fs *= 2.0f;
            s_pos[pt][f * 6 + a]     = (sv  + 1.0f) * 63.5f;   // sin row
            s_pos[pt][f * 6 + 3 + a] = (cvv + 1.0f) * 63.5f;   // cos row
        }
    }
    __syncthreads();

    // ---- phase 1: one (pp, jj) per thread; pp covers points 2pp, 2pp+1 ----
    if (t < (PTB / 2) * NJ) {
        const int pp = t / NJ, jj = t - pp * NJ;
        const int f = jj / 6, k = jj - f * 6;
        static constexpr int XI[6] = {1, 2, 0, 4, 5, 3};
        static constexpr int YI[6] = {2, 0, 1, 5, 3, 4};
        const int jx = f * 6 + XI[k], jy = f * 6 + YI[k];
        const int ptA = pp * 2, ptB = ptA + 1;

        float pvA = s_pos[ptA][jj], pxA = s_pos[ptA][jx], pyA = s_pos[ptA][jy];
        float pvB = s_pos[ptB][jj], pxB = s_pos[ptB][jx], pyB = s_pos[ptB][jy];

        int ivA = min((int)pvA, 127); float wvA = pvA - (float)ivA;
        int ixA = min((int)pxA, 127); float wxA = pxA - (float)ixA;
        int iyA = min((int)pyA, 127); float wyA = pyA - (float)iyA;
        int ivB = min((int)pvB, 127); float wvB = pvB - (float)ivB;
        int ixB = min((int)pxB, 127); float wxB = pxB - (float)ixB;
        int iyB = min((int)pyB, 127); float wyB = pyB - (float)iyB;

        // one aligned 8B load per bilinear (clamp baked into table)
        const uint2u8* mjb = cm2 + ((size_t)jj << 14);
        uint2u8 RA = mjb[(iyA << 7) + ixA];
        uint2u8 RB = mjb[(iyB << 7) + ixB];

        // cv endpoints from LDS (exact clamp semantics)
        const unsigned* cvj = s_cv + jj * 128;
        unsigned v0A_ = cvj[ivA], v1A_ = cvj[min(ivA + 1, 127)];
        unsigned v0B_ = cvj[ivB], v1B_ = cvj[min(ivB + 1, 127)];

        unsigned loA = RA.x, hiA = RA.y;
        unsigned loB = RB.x, hiB = RB.y;
        float* orowA = s_out + ptA * ROW + 3 + jj;
        float* orowB = s_out + ptB * ROW + 3 + jj;

#pragma unroll
        for (int cc = 0; cc < 8; ++cc) {
            {
                float m00 = (float)(loA & 3u), m01 = (float)((loA >> 16) & 3u);
                float m10 = (float)(hiA & 3u), m11 = (float)((hiA >> 16) & 3u);
                float v0 = (float)(v0A_ & 15u), v1 = (float)(v1A_ & 15u);
                float x0 = m00 + (m01 - m00) * wxA;
                float x1 = m10 + (m11 - m10) * wxA;
                float m  = x0 + (x1 - x0) * wyA - 1.5f;
                float v  = v0 + (v1 - v0) * wvA - 7.5f;
                orowA[cc * 36] = m * v * QQ;
            }
            {
                float m00 = (float)(loB & 3u), m01 = (float)((loB >> 16) & 3u);
                float m10 = (float)(hiB & 3u), m11 = (float)((hiB >> 16) & 3u);
                float v0 = (float)(v0B_ & 15u), v1 = (float)(v1B_ & 15u);
                float x0 = m00 + (m01 - m00) * wxB;
                float x1 = m10 + (m11 - m10) * wxB;
                float m  = x0 + (x1 - x0) * wyB - 1.5f;
                float v  = v0 + (v1 - v0) * wvB - 7.5f;
                orowB[cc * 36] = m * v * QQ;
            }
            loA >>= 2; hiA >>= 2; v0A_ >>= 4; v1A_ >>= 4;
            loB >>= 2; hiB >>= 2; v0B_ >>= 4; v1B_ >>= 4;
        }
    }
    __syncthreads();

    // ---- phase 2: vectorized non-temporal writeout ----
    size_t base  = (size_t)blk * (PTB * ROW);
    size_t total = (size_t)n * ROW;
    size_t rem   = total - base;
    float* o = out + base;
    if (rem >= (size_t)(PTB * ROW)) {
        const int head = (int)(base & 3);                 // 0 or 2
        if (head) {
            if (t == 0) {
                __builtin_nontemporal_store(s_out[0], &o[0]);
                __builtin_nontemporal_store(s_out[1], &o[1]);
            }
        }
        const float* sv = s_out + head;
        f32x4* o4 = (f32x4*)(o + head);
        for (int i = t; i < 1018; i += THREADS) {
            f32x4 v = { sv[4 * i], sv[4 * i + 1], sv[4 * i + 2], sv[4 * i + 3] };
            __builtin_nontemporal_store(v, &o4[i]);
        }
        if (!head) {
            if (t == THREADS - 1) {
                __builtin_nontemporal_store(s_out[4072], &o[4072]);
                __builtin_nontemporal_store(s_out[4073], &o[4073]);
            }
        }
    } else {
        int lim = (int)rem;
        for (int i = t; i < lim; i += THREADS)
            __builtin_nontemporal_store(s_out[i], &o[i]);
    }
}

// ---------------- fallback (no workspace): fp32 original layout ----------------
__global__ __launch_bounds__(256) void freqvm_slow(
    const float* __restrict__ points,
    const float* __restrict__ cv,    // [j][c][i]
    const float* __restrict__ cm,    // [j][c][y][x]
    float* __restrict__ out, int n)
{
    __shared__ float s_pos[32][NJ];
    __shared__ __align__(16) float s_out[32 * ROW];
    const int t  = threadIdx.x;
    const int p0 = blockIdx.x * 32;
    if (t < 96) {
        int pt = t / 3, a = t - pt * 3;
        int gp = p0 + pt;
        float x = (gp < n) ? points[gp * 3 + a] : 0.0f;
        s_out[pt * ROW + a] = x;
#pragma unroll
        for (int f = 0; f < 6; ++f) {
            float sv, cvv;
            __sincosf(x * (float)(1 << f), &sv, &cvv);
            s_pos[pt][f * 6 + a]     = (sv  + 1.0f) * 63.5f;
            s_pos[pt][f * 6 + 3 + a] = (cvv + 1.0f) * 63.5f;
        }
    }
    __syncthreads();
    static constexpr int XI[6] = {1, 2, 0, 4, 5, 3};
    static constexpr int YI[6] = {2, 0, 1, 5, 3, 4};
    const int c  = t & 7;
    const int pt = t >> 3;
    for (int f = 0; f < 6; ++f) {
#pragma unroll
        for (int k = 0; k < 6; ++k) {
            const int j = f * 6 + k;
            float pj = s_pos[pt][j];
            int   i0 = min((int)pj, 127); float wv = pj - (float)i0;
            int   i1 = min(i0 + 1, 127);
            const float* vb = cv + (size_t)(j * 8 + c) * 128;
            float vecf = vb[i0] + (vb[i1] - vb[i0]) * wv;
            float px = s_pos[pt][f * 6 + XI[k]];
            float py = s_pos[pt][f * 6 + YI[k]];
            int   ix0 = min((int)px, 127); float wx = px - (float)ix0;
            int   iy0 = min((int)py, 127); float wy = py - (float)iy0;
            int   ix1 = min(ix0 + 1, 127);
            int   iy1 = min(iy0 + 1, 127);
            const float* mb = cm + (size_t)(j * 8 + c) * 16384;
            float m00 = mb[iy0 * 128 + ix0], m01 = mb[iy0 * 128 + ix1];
            float m10 = mb[iy1 * 128 + ix0], m11 = mb[iy1 * 128 + ix1];
            float mx0  = m00 + (m01 - m00) * wx;
            float mx1  = m10 + (m11 - m10) * wx;
            s_out[pt * ROW + 3 + c * 36 + j] = vecf * (mx0 + (mx1 - mx0) * wy);
        }
    }
    __syncthreads();
    size_t base  = (size_t)blockIdx.x * (32 * ROW);
    size_t total = (size_t)n * ROW;
    size_t rem   = total - base;
    int lim = (int)((rem < (size_t)(32 * ROW) ? rem : (size_t)(32 * ROW)));
    float* o = out + base;
    for (int i = t; i < lim; i += 256) o[i] = s_out[i];
}

extern "C" void kernel_launch(void* const* d_in, const int* in_sizes, int n_in,
                              void* d_out, int out_size, void* d_ws, size_t ws_size,
                              hipStream_t stream) {
    (void)n_in; (void)out_size;
    const float* points = (const float*)d_in[0];
    const float* cv     = (const float*)d_in[1];
    const float* cm     = (const float*)d_in[2];
    float* out = (float*)d_out;
    const int n = in_sizes[0] / 3;

    const size_t cm2_bytes = (size_t)NJ * 16384 * 8;   // 4.72 MB (uint2 4-corner unit)
    const size_t q2_bytes  = (size_t)NJ * 16384 * 2;   // 1.18 MB scratch
    const size_t cv_bytes  = (size_t)NJ * 128 * 4;     // 18.4 KB

    if (ws_size >= cm2_bytes + q2_bytes + cv_bytes + 64) {
        uint2*          cm2 = (uint2*)d_ws;
        unsigned short* q2s = (unsigned short*)((char*)d_ws + cm2_bytes);
        unsigned int*   cvn = (unsigned int*)((char*)d_ws + cm2_bytes + q2_bytes);
        t_q2k<<<NJ * 64, 256, 0, stream>>>(cm, q2s);
        t_c4k<<<NJ * 64, 256, 0, stream>>>(q2s, cm2);
        t_cvn<<<NJ,      128, 0, stream>>>(cv, cvn);
        int nblocks = (n + PTB - 1) / PTB;
        freqvm_v11<<<nblocks, THREADS, 0, stream>>>(points, cvn, (const uint2u8*)cm2,
                                                    out, n);
    } else {
        int nblocks = (n + 31) / 32;
        freqvm_slow<<<nblocks, 256, 0, stream>>>(points, cv, cm, out, n);
    }
}

// Round 12
// 107.864 us; speedup vs baseline: 1.1303x; 1.0680x over previous
//
#include <hip/hip_runtime.h>
#include <math.h>

#define NJ      36
#define PTB     14          // points per block (two per j-thread)
#define ROW     291
#define THREADS 256
#define QSM     0.0025f     // 2-bit cm scale
#define QSV     0.0008f     // 4-bit cv scale
#define QQ      (QSM * QSV)

typedef float f32x4 __attribute__((ext_vector_type(4)));
typedef unsigned int uint32x2 __attribute__((ext_vector_type(2)));
typedef uint32x2 uint2u8 __attribute__((aligned(8)));

__device__ __forceinline__ unsigned q2nib(float x) {
    float q = rintf(x * (1.0f / QSM) + 1.5f);
    q = fminf(fmaxf(q, 0.0f), 3.0f);
    return (unsigned)q;
}
__device__ __forceinline__ unsigned q4nib(float x) {
    float q = rintf(x * (1.0f / QSV) + 7.5f);
    q = fminf(fmaxf(q, 0.0f), 15.0f);
    return (unsigned)q;
}

// ---- pass 1: cm (36,8,128,128) f32 -> q2 rowpack u16 [36][16384] ----
__global__ __launch_bounds__(256) void t_q2k(const float* __restrict__ src,
                                             unsigned short* __restrict__ dst) {
    __shared__ float tile[8][260];
    int j    = blockIdx.x >> 6;
    int pix0 = (blockIdx.x & 63) << 8;
    int t    = threadIdx.x;
    const float* s = src + (size_t)j * (8 * 16384) + pix0;
#pragma unroll
    for (int r = 0; r < 8; ++r) tile[r][t] = s[(size_t)r * 16384 + t];
    __syncthreads();
    unsigned u = 0;
#pragma unroll
    for (int r = 0; r < 8; ++r) u |= q2nib(tile[r][t]) << (2 * r);
    dst[j * 16384 + pix0 + t] = (unsigned short)u;
}

// ---- pass 2: build 4-corner 8B units (clamp baked in): uint2 [36][16384] ----
// lo = {row y: x, x+1}, hi = {row y+1: x, x+1}; channel c at bits 2c / 16+2c
__global__ __launch_bounds__(256) void t_c4k(const unsigned short* __restrict__ q,
                                             uint2* __restrict__ dst) {
    int j = blockIdx.x >> 6;
    int p = ((blockIdx.x & 63) << 8) + threadIdx.x;
    int y = p >> 7, x = p & 127;
    int xn = min(x + 1, 127), yn = min(y + 1, 127);
    const unsigned short* qj = q + j * 16384;
    unsigned lo = (unsigned)qj[(y  << 7) + x] | ((unsigned)qj[(y  << 7) + xn] << 16);
    unsigned hi = (unsigned)qj[(yn << 7) + x] | ((unsigned)qj[(yn << 7) + xn] << 16);
    dst[j * 16384 + p] = make_uint2(lo, hi);
}

// ---- cv (36,8,128) f32 -> cv4 (36,128) uint2 {q(i), q(i+1)} 4-bit nibbles ----
__global__ __launch_bounds__(128) void t_cv4k(const float* __restrict__ src,
                                              uint2* __restrict__ dst) {
    __shared__ unsigned int spk[128];
    int j = blockIdx.x, i = threadIdx.x;
    unsigned int u = 0;
#pragma unroll
    for (int c = 0; c < 8; ++c) u |= q4nib(src[j * 1024 + c * 128 + i]) << (4 * c);
    spk[i] = u;
    __syncthreads();
    dst[j * 128 + i] = make_uint2(u, spk[min(i + 1, 127)]);
}

// ---- v12: one 8B cm load + one 8B cv load per bilinear; 8 blocks/CU ----
__global__ __launch_bounds__(THREADS, 8) void freqvm_v12(
    const float* __restrict__ points,
    const uint2u8* __restrict__ cv4,         // [j][i] {q(i),q(i+1)} nibbles
    const uint2u8* __restrict__ cm2,         // [j][y*128+x] 4-corner 2-bit units
    float* __restrict__ out, int n)
{
    __shared__ float s_pos[PTB][NJ];                      // 2016 B
    __shared__ __align__(16) float s_out[PTB * ROW];      // 16296 B

    const int t   = threadIdx.x;
    const int blk = blockIdx.x;

    // ---- phase 0: sincos once per point (42 threads) ----
    if (t < PTB * 3) {
        int pt = t / 3, a = t - pt * 3;
        int gp  = blk * PTB + pt;
        int gpc = (gp < n) ? gp : (n - 1);
        float x = points[gpc * 3 + a];
        s_out[pt * ROW + a] = x;                          // passthrough coords
        float fs = 1.0f;
#pragma unroll
        for (int f = 0; f < 6; ++f) {
            float sv, cvv;
            __sincosf(x * fs, &sv, &cvv);
            fs *= 2.0f;
            s_pos[pt][f * 6 + a]     = (sv  + 1.0f) * 63.5f;   // sin row
            s_pos[pt][f * 6 + 3 + a] = (cvv + 1.0f) * 63.5f;   // cos row
        }
    }
    __syncthreads();

    // ---- phase 1: one (pp, jj) per thread; pp covers points 2pp, 2pp+1 ----
    if (t < (PTB / 2) * NJ) {
        const int pp = t / NJ, jj = t - pp * NJ;
        const int f = jj / 6, k = jj - f * 6;
        static constexpr int XI[6] = {1, 2, 0, 4, 5, 3};
        static constexpr int YI[6] = {2, 0, 1, 5, 3, 4};
        const int jx = f * 6 + XI[k], jy = f * 6 + YI[k];
        const int ptA = pp * 2, ptB = ptA + 1;

        float pvA = s_pos[ptA][jj], pxA = s_pos[ptA][jx], pyA = s_pos[ptA][jy];
        float pvB = s_pos[ptB][jj], pxB = s_pos[ptB][jx], pyB = s_pos[ptB][jy];

        int ivA = min((int)pvA, 127); float wvA = pvA - (float)ivA;
        int ixA = min((int)pxA, 127); float wxA = pxA - (float)ixA;
        int iyA = min((int)pyA, 127); float wyA = pyA - (float)iyA;
        int ivB = min((int)pvB, 127); float wvB = pvB - (float)ivB;
        int ixB = min((int)pxB, 127); float wxB = pxB - (float)ixB;
        int iyB = min((int)pyB, 127); float wyB = pyB - (float)iyB;

        // issue all 4 independent 8B loads back-to-back
        const uint2u8* mjb = cm2 + ((size_t)jj << 14);
        const uint2u8* vjb = cv4 + ((size_t)jj << 7);
        uint2u8 RA = mjb[(iyA << 7) + ixA];
        uint2u8 RB = mjb[(iyB << 7) + ixB];
        uint2u8 VA = vjb[ivA];
        uint2u8 VB = vjb[ivB];

        unsigned loA = RA.x, hiA = RA.y, v0A_ = VA.x, v1A_ = VA.y;
        unsigned loB = RB.x, hiB = RB.y, v0B_ = VB.x, v1B_ = VB.y;
        float* orowA = s_out + ptA * ROW + 3 + jj;
        float* orowB = s_out + ptB * ROW + 3 + jj;

#pragma unroll
        for (int cc = 0; cc < 8; ++cc) {
            {
                float m00 = (float)(loA & 3u), m01 = (float)((loA >> 16) & 3u);
                float m10 = (float)(hiA & 3u), m11 = (float)((hiA >> 16) & 3u);
                float v0 = (float)(v0A_ & 15u), v1 = (float)(v1A_ & 15u);
                float x0 = m00 + (m01 - m00) * wxA;
                float x1 = m10 + (m11 - m10) * wxA;
                float m  = x0 + (x1 - x0) * wyA - 1.5f;
                float v  = v0 + (v1 - v0) * wvA - 7.5f;
                orowA[cc * 36] = m * v * QQ;
            }
            {
                float m00 = (float)(loB & 3u), m01 = (float)((loB >> 16) & 3u);
                float m10 = (float)(hiB & 3u), m11 = (float)((hiB >> 16) & 3u);
                float v0 = (float)(v0B_ & 15u), v1 = (float)(v1B_ & 15u);
                float x0 = m00 + (m01 - m00) * wxB;
                float x1 = m10 + (m11 - m10) * wxB;
                float m  = x0 + (x1 - x0) * wyB - 1.5f;
                float v  = v0 + (v1 - v0) * wvB - 7.5f;
                orowB[cc * 36] = m * v * QQ;
            }
            loA >>= 2; hiA >>= 2; v0A_ >>= 4; v1A_ >>= 4;
            loB >>= 2; hiB >>= 2; v0B_ >>= 4; v1B_ >>= 4;
        }
    }
    __syncthreads();

    // ---- phase 2: vectorized non-temporal writeout ----
    size_t base  = (size_t)blk * (PTB * ROW);
    size_t total = (size_t)n * ROW;
    size_t rem   = total - base;
    float* o = out + base;
    if (rem >= (size_t)(PTB * ROW)) {
        const int head = (int)(base & 3);                 // 0 or 2
        if (head) {
            if (t == 0) {
                __builtin_nontemporal_store(s_out[0], &o[0]);
                __builtin_nontemporal_store(s_out[1], &o[1]);
            }
        }
        const float* sv = s_out + head;
        f32x4* o4 = (f32x4*)(o + head);
        for (int i = t; i < 1018; i += THREADS) {
            f32x4 v = { sv[4 * i], sv[4 * i + 1], sv[4 * i + 2], sv[4 * i + 3] };
            __builtin_nontemporal_store(v, &o4[i]);
        }
        if (!head) {
            if (t == THREADS - 1) {
                __builtin_nontemporal_store(s_out[4072], &o[4072]);
                __builtin_nontemporal_store(s_out[4073], &o[4073]);
            }
        }
    } else {
        int lim = (int)rem;
        for (int i = t; i < lim; i += THREADS)
            __builtin_nontemporal_store(s_out[i], &o[i]);
    }
}

// ---------------- fallback (no workspace): fp32 original layout ----------------
__global__ __launch_bounds__(256) void freqvm_slow(
    const float* __restrict__ points,
    const float* __restrict__ cv,    // [j][c][i]
    const float* __restrict__ cm,    // [j][c][y][x]
    float* __restrict__ out, int n)
{
    __shared__ float s_pos[32][NJ];
    __shared__ __align__(16) float s_out[32 * ROW];
    const int t  = threadIdx.x;
    const int p0 = blockIdx.x * 32;
    if (t < 96) {
        int pt = t / 3, a = t - pt * 3;
        int gp = p0 + pt;
        float x = (gp < n) ? points[gp * 3 + a] : 0.0f;
        s_out[pt * ROW + a] = x;
#pragma unroll
        for (int f = 0; f < 6; ++f) {
            float sv, cvv;
            __sincosf(x * (float)(1 << f), &sv, &cvv);
            s_pos[pt][f * 6 + a]     = (sv  + 1.0f) * 63.5f;
            s_pos[pt][f * 6 + 3 + a] = (cvv + 1.0f) * 63.5f;
        }
    }
    __syncthreads();
    static constexpr int XI[6] = {1, 2, 0, 4, 5, 3};
    static constexpr int YI[6] = {2, 0, 1, 5, 3, 4};
    const int c  = t & 7;
    const int pt = t >> 3;
    for (int f = 0; f < 6; ++f) {
#pragma unroll
        for (int k = 0; k < 6; ++k) {
            const int j = f * 6 + k;
            float pj = s_pos[pt][j];
            int   i0 = min((int)pj, 127); float wv = pj - (float)i0;
            int   i1 = min(i0 + 1, 127);
            const float* vb = cv + (size_t)(j * 8 + c) * 128;
            float vecf = vb[i0] + (vb[i1] - vb[i0]) * wv;
            float px = s_pos[pt][f * 6 + XI[k]];
            float py = s_pos[pt][f * 6 + YI[k]];
            int   ix0 = min((int)px, 127); float wx = px - (float)ix0;
            int   iy0 = min((int)py, 127); float wy = py - (float)iy0;
            int   ix1 = min(ix0 + 1, 127);
            int   iy1 = min(iy0 + 1, 127);
            const float* mb = cm + (size_t)(j * 8 + c) * 16384;
            float m00 = mb[iy0 * 128 + ix0], m01 = mb[iy0 * 128 + ix1];
            float m10 = mb[iy1 * 128 + ix0], m11 = mb[iy1 * 128 + ix1];
            float mx0  = m00 + (m01 - m00) * wx;
            float mx1  = m10 + (m11 - m10) * wx;
            s_out[pt * ROW + 3 + c * 36 + j] = vecf * (mx0 + (mx1 - mx0) * wy);
        }
    }
    __syncthreads();
    size_t base  = (size_t)blockIdx.x * (32 * ROW);
    size_t total = (size_t)n * ROW;
    size_t rem   = total - base;
    int lim = (int)((rem < (size_t)(32 * ROW) ? rem : (size_t)(32 * ROW)));
    float* o = out + base;
    for (int i = t; i < lim; i += 256) o[i] = s_out[i];
}

extern "C" void kernel_launch(void* const* d_in, const int* in_sizes, int n_in,
                              void* d_out, int out_size, void* d_ws, size_t ws_size,
                              hipStream_t stream) {
    (void)n_in; (void)out_size;
    const float* points = (const float*)d_in[0];
    const float* cv     = (const float*)d_in[1];
    const float* cm     = (const float*)d_in[2];
    float* out = (float*)d_out;
    const int n = in_sizes[0] / 3;

    const size_t cm2_bytes = (size_t)NJ * 16384 * 8;   // 4.72 MB (4-corner units)
    const size_t q2_bytes  = (size_t)NJ * 16384 * 2;   // 1.18 MB scratch
    const size_t cv_bytes  = (size_t)NJ * 128 * 8;     // 36.9 KB

    if (ws_size >= cm2_bytes + q2_bytes + cv_bytes + 64) {
        uint2*          cm2 = (uint2*)d_ws;
        unsigned short* q2s = (unsigned short*)((char*)d_ws + cm2_bytes);
        uint2*          cv4 = (uint2*)((char*)d_ws + cm2_bytes + q2_bytes);
        t_q2k <<<NJ * 64, 256, 0, stream>>>(cm, q2s);
        t_c4k <<<NJ * 64, 256, 0, stream>>>(q2s, cm2);
        t_cv4k<<<NJ,      128, 0, stream>>>(cv, cv4);
        int nblocks = (n + PTB - 1) / PTB;
        freqvm_v12<<<nblocks, THREADS, 0, stream>>>(points, (const uint2u8*)cv4,
                                                    (const uint2u8*)cm2, out, n);
    } else {
        int nblocks = (n + 31) / 32;
        freqvm_slow<<<nblocks, 256, 0, stream>>>(points, cv, cm, out, n);
    }
}

// Round 13
// 102.576 us; speedup vs baseline: 1.1886x; 1.0515x over previous
//
#include <hip/hip_runtime.h>
#include <math.h>

#define NJ      36
#define PTB     14          // points per block (two per j-thread)
#define ROW     291
#define THREADS 256
#define QSM     0.0025f     // 2-bit quant scale (cm and cv)
#define QQ      (QSM * QSM)

typedef float f32x4 __attribute__((ext_vector_type(4)));
typedef unsigned int uint32x2 __attribute__((ext_vector_type(2)));
typedef uint32x2 uint2u8 __attribute__((aligned(8)));

__device__ __forceinline__ unsigned q2nib(float x) {
    float q = rintf(x * (1.0f / QSM) + 1.5f);
    q = fminf(fmaxf(q, 0.0f), 3.0f);
    return (unsigned)q;
}

// ---- pass 1: cm (36,8,128,128) f32 -> q2 rowpack u16 [36][16384] ----
__global__ __launch_bounds__(256) void t_q2k(const float* __restrict__ src,
                                             unsigned short* __restrict__ dst) {
    __shared__ float tile[8][260];
    int j    = blockIdx.x >> 6;
    int pix0 = (blockIdx.x & 63) << 8;
    int t    = threadIdx.x;
    const float* s = src + (size_t)j * (8 * 16384) + pix0;
#pragma unroll
    for (int r = 0; r < 8; ++r) tile[r][t] = s[(size_t)r * 16384 + t];
    __syncthreads();
    unsigned u = 0;
#pragma unroll
    for (int r = 0; r < 8; ++r) u |= q2nib(tile[r][t]) << (2 * r);
    dst[j * 16384 + pix0 + t] = (unsigned short)u;
}

// ---- pass 2: build 4-corner 8B units (clamp baked in): uint2 [36][16384] ----
// lo = {row y: x, x+1}, hi = {row y+1: x, x+1}; channel c at bits 2c / 16+2c
__global__ __launch_bounds__(256) void t_c4k(const unsigned short* __restrict__ q,
                                             uint2* __restrict__ dst) {
    int j = blockIdx.x >> 6;
    int p = ((blockIdx.x & 63) << 8) + threadIdx.x;
    int y = p >> 7, x = p & 127;
    int xn = min(x + 1, 127), yn = min(y + 1, 127);
    const unsigned short* qj = q + j * 16384;
    unsigned lo = (unsigned)qj[(y  << 7) + x] | ((unsigned)qj[(y  << 7) + xn] << 16);
    unsigned hi = (unsigned)qj[(yn << 7) + x] | ((unsigned)qj[(yn << 7) + xn] << 16);
    dst[j * 16384 + p] = make_uint2(lo, hi);
}

// ---- cv (36,8,128) f32 -> cvr (36,128) u32 {q2(i) lo16, q2(i+1) hi16} ----
__global__ __launch_bounds__(128) void t_cv2k(const float* __restrict__ src,
                                              unsigned int* __restrict__ dst) {
    __shared__ unsigned short spk[128];
    int j = blockIdx.x, i = threadIdx.x;
    unsigned u = 0;
#pragma unroll
    for (int c = 0; c < 8; ++c) u |= q2nib(src[j * 1024 + c * 128 + i]) << (2 * c);
    spk[i] = (unsigned short)u;
    __syncthreads();
    dst[j * 128 + i] = (unsigned)spk[i] | ((unsigned)spk[min(i + 1, 127)] << 16);
}

// ---- v13: one 8B cm load + one 4B L1-resident cv load per bilinear ----
__global__ __launch_bounds__(THREADS, 8) void freqvm_v13(
    const float* __restrict__ points,
    const unsigned int* __restrict__ cvr,    // [j][i] 2-bit pair-replicated
    const uint2u8* __restrict__ cm2,         // [j][y*128+x] 4-corner 2-bit units
    float* __restrict__ out, int n)
{
    __shared__ float s_pos[PTB][NJ];                      // 2016 B
    __shared__ __align__(16) float s_out[PTB * ROW];      // 16296 B

    const int t   = threadIdx.x;
    const int blk = blockIdx.x;

    // ---- phase 0: sincos once per point (42 threads) ----
    if (t < PTB * 3) {
        int pt = t / 3, a = t - pt * 3;
        int gp  = blk * PTB + pt;
        int gpc = (gp < n) ? gp : (n - 1);
        float x = points[gpc * 3 + a];
        s_out[pt * ROW + a] = x;                          // passthrough coords
        float fs = 1.0f;
#pragma unroll
        for (int f = 0; f < 6; ++f) {
            float sv, cvv;
            __sincosf(x * fs, &sv, &cvv);
            fs *= 2.0f;
            s_pos[pt][f * 6 + a]     = (sv  + 1.0f) * 63.5f;   // sin row
            s_pos[pt][f * 6 + 3 + a] = (cvv + 1.0f) * 63.5f;   // cos row
        }
    }
    __syncthreads();

    // ---- phase 1: one (pp, jj) per thread; pp covers points 2pp, 2pp+1 ----
    if (t < (PTB / 2) * NJ) {
        const int pp = t / NJ, jj = t - pp * NJ;
        const int f = jj / 6, k = jj - f * 6;
        static constexpr int XI[6] = {1, 2, 0, 4, 5, 3};
        static constexpr int YI[6] = {2, 0, 1, 5, 3, 4};
        const int jx = f * 6 + XI[k], jy = f * 6 + YI[k];
        const int ptA = pp * 2, ptB = ptA + 1;

        float pvA = s_pos[ptA][jj], pxA = s_pos[ptA][jx], pyA = s_pos[ptA][jy];
        float pvB = s_pos[ptB][jj], pxB = s_pos[ptB][jx], pyB = s_pos[ptB][jy];

        int ivA = min((int)pvA, 127); float wvA = pvA - (float)ivA;
        int ixA = min((int)pxA, 127); float wxA = pxA - (float)ixA;
        int iyA = min((int)pyA, 127); float wyA = pyA - (float)iyA;
        int ivB = min((int)pvB, 127); float wvB = pvB - (float)ivB;
        int ixB = min((int)pxB, 127); float wxB = pxB - (float)ixB;
        int iyB = min((int)pyB, 127); float wyB = pyB - (float)iyB;

        // issue all 4 independent loads back-to-back
        const uint2u8*  mjb = cm2 + ((size_t)jj << 14);
        const unsigned* vjb = cvr + (jj << 7);
        uint2u8 RA = mjb[(iyA << 7) + ixA];
        uint2u8 RB = mjb[(iyB << 7) + ixB];
        unsigned VA = vjb[ivA];
        unsigned VB = vjb[ivB];

        unsigned loA = RA.x, hiA = RA.y;
        unsigned loB = RB.x, hiB = RB.y;
        float* orowA = s_out + ptA * ROW + 3 + jj;
        float* orowB = s_out + ptB * ROW + 3 + jj;

#pragma unroll
        for (int cc = 0; cc < 8; ++cc) {
            {
                float m00 = (float)(loA & 3u), m01 = (float)((loA >> 16) & 3u);
                float m10 = (float)(hiA & 3u), m11 = (float)((hiA >> 16) & 3u);
                float v0  = (float)(VA & 3u),  v1  = (float)((VA >> 16) & 3u);
                float x0 = m00 + (m01 - m00) * wxA;
                float x1 = m10 + (m11 - m10) * wxA;
                float m  = x0 + (x1 - x0) * wyA - 1.5f;
                float v  = v0 + (v1 - v0) * wvA - 1.5f;
                orowA[cc * 36] = m * v * QQ;
            }
            {
                float m00 = (float)(loB & 3u), m01 = (float)((loB >> 16) & 3u);
                float m10 = (float)(hiB & 3u), m11 = (float)((hiB >> 16) & 3u);
                float v0  = (float)(VB & 3u),  v1  = (float)((VB >> 16) & 3u);
                float x0 = m00 + (m01 - m00) * wxB;
                float x1 = m10 + (m11 - m10) * wxB;
                float m  = x0 + (x1 - x0) * wyB - 1.5f;
                float v  = v0 + (v1 - v0) * wvB - 1.5f;
                orowB[cc * 36] = m * v * QQ;
            }
            loA >>= 2; hiA >>= 2; VA >>= 2;
            loB >>= 2; hiB >>= 2; VB >>= 2;
        }
    }
    __syncthreads();

    // ---- phase 2: vectorized non-temporal writeout ----
    size_t base  = (size_t)blk * (PTB * ROW);
    size_t total = (size_t)n * ROW;
    size_t rem   = total - base;
    float* o = out + base;
    if (rem >= (size_t)(PTB * ROW)) {
        const int head = (int)(base & 3);                 // 0 or 2
        if (head) {
            if (t == 0) {
                __builtin_nontemporal_store(s_out[0], &o[0]);
                __builtin_nontemporal_store(s_out[1], &o[1]);
            }
        }
        const float* sv = s_out + head;
        f32x4* o4 = (f32x4*)(o + head);
        for (int i = t; i < 1018; i += THREADS) {
            f32x4 v = { sv[4 * i], sv[4 * i + 1], sv[4 * i + 2], sv[4 * i + 3] };
            __builtin_nontemporal_store(v, &o4[i]);
        }
        if (!head) {
            if (t == THREADS - 1) {
                __builtin_nontemporal_store(s_out[4072], &o[4072]);
                __builtin_nontemporal_store(s_out[4073], &o[4073]);
            }
        }
    } else {
        int lim = (int)rem;
        for (int i = t; i < lim; i += THREADS)
            __builtin_nontemporal_store(s_out[i], &o[i]);
    }
}

// ---------------- fallback (no workspace): fp32 original layout ----------------
__global__ __launch_bounds__(256) void freqvm_slow(
    const float* __restrict__ points,
    const float* __restrict__ cv,    // [j][c][i]
    const float* __restrict__ cm,    // [j][c][y][x]
    float* __restrict__ out, int n)
{
    __shared__ float s_pos[32][NJ];
    __shared__ __align__(16) float s_out[32 * ROW];
    const int t  = threadIdx.x;
    const int p0 = blockIdx.x * 32;
    if (t < 96) {
        int pt = t / 3, a = t - pt * 3;
        int gp = p0 + pt;
        float x = (gp < n) ? points[gp * 3 + a] : 0.0f;
        s_out[pt * ROW + a] = x;
#pragma unroll
        for (int f = 0; f < 6; ++f) {
            float sv, cvv;
            __sincosf(x * (float)(1 << f), &sv, &cvv);
            s_pos[pt][f * 6 + a]     = (sv  + 1.0f) * 63.5f;
            s_pos[pt][f * 6 + 3 + a] = (cvv + 1.0f) * 63.5f;
        }
    }
    __syncthreads();
    static constexpr int XI[6] = {1, 2, 0, 4, 5, 3};
    static constexpr int YI[6] = {2, 0, 1, 5, 3, 4};
    const int c  = t & 7;
    const int pt = t >> 3;
    for (int f = 0; f < 6; ++f) {
#pragma unroll
        for (int k = 0; k < 6; ++k) {
            const int j = f * 6 + k;
            float pj = s_pos[pt][j];
            int   i0 = min((int)pj, 127); float wv = pj - (float)i0;
            int   i1 = min(i0 + 1, 127);
            const float* vb = cv + (size_t)(j * 8 + c) * 128;
            float vecf = vb[i0] + (vb[i1] - vb[i0]) * wv;
            float px = s_pos[pt][f * 6 + XI[k]];
            float py = s_pos[pt][f * 6 + YI[k]];
            int   ix0 = min((int)px, 127); float wx = px - (float)ix0;
            int   iy0 = min((int)py, 127); float wy = py - (float)iy0;
            int   ix1 = min(ix0 + 1, 127);
            int   iy1 = min(iy0 + 1, 127);
            const float* mb = cm + (size_t)(j * 8 + c) * 16384;
            float m00 = mb[iy0 * 128 + ix0], m01 = mb[iy0 * 128 + ix1];
            float m10 = mb[iy1 * 128 + ix0], m11 = mb[iy1 * 128 + ix1];
            float mx0  = m00 + (m01 - m00) * wx;
            float mx1  = m10 + (m11 - m10) * wx;
            s_out[pt * ROW + 3 + c * 36 + j] = vecf * (mx0 + (mx1 - mx0) * wy);
        }
    }
    __syncthreads();
    size_t base  = (size_t)blockIdx.x * (32 * ROW);
    size_t total = (size_t)n * ROW;
    size_t rem   = total - base;
    int lim = (int)((rem < (size_t)(32 * ROW) ? rem : (size_t)(32 * ROW)));
    float* o = out + base;
    for (int i = t; i < lim; i += 256) o[i] = s_out[i];
}

extern "C" void kernel_launch(void* const* d_in, const int* in_sizes, int n_in,
                              void* d_out, int out_size, void* d_ws, size_t ws_size,
                              hipStream_t stream) {
    (void)n_in; (void)out_size;
    const float* points = (const float*)d_in[0];
    const float* cv     = (const float*)d_in[1];
    const float* cm     = (const float*)d_in[2];
    float* out = (float*)d_out;
    const int n = in_sizes[0] / 3;

    const size_t cm2_bytes = (size_t)NJ * 16384 * 8;   // 4.72 MB (4-corner units)
    const size_t q2_bytes  = (size_t)NJ * 16384 * 2;   // 1.18 MB scratch
    const size_t cv_bytes  = (size_t)NJ * 128 * 4;     // 18.4 KB

    if (ws_size >= cm2_bytes + q2_bytes + cv_bytes + 64) {
        uint2*          cm2 = (uint2*)d_ws;
        unsigned short* q2s = (unsigned short*)((char*)d_ws + cm2_bytes);
        unsigned int*   cvr = (unsigned int*)((char*)d_ws + cm2_bytes + q2_bytes);
        t_q2k <<<NJ * 64, 256, 0, stream>>>(cm, q2s);
        t_c4k <<<NJ * 64, 256, 0, stream>>>(q2s, cm2);
        t_cv2k<<<NJ,      128, 0, stream>>>(cv, cvr);
        int nblocks = (n + PTB - 1) / PTB;
        freqvm_v13<<<nblocks, THREADS, 0, stream>>>(points, cvr,
                                                    (const uint2u8*)cm2, out, n);
    } else {
        int nblocks = (n + 31) / 32;
        freqvm_slow<<<nblocks, 256, 0, stream>>>(points, cv, cm, out, n);
    }
}